// Round 10
// baseline (1593.966 us; speedup 1.0000x reference)
//
#include <hip/hip_runtime.h>

// LSTM B=128,T=1024,H=128,D=64,L=3 — fused, layer-pipelined, R16.
// R16 change: HIDE the chunk GEMM inside the recurrence steps. The A-tile
// for chunk ck+1 is staged in LDS at u==10 of chunk ck (prefetch drain) —
// but the xg GEMM for ck+1 ran serially at ck+1's top (~1.5-2us). Now:
// steps 12..15 each run ONE M-tile of next chunk's GEMM (16 MFMA + LDS ops,
// dependence-free vs the recurrence chain -> fills the ~70% per-step stall;
// 2 waves/SIMD have nothing else to fill it, see R14 post-mortem). Steady-
// state chunk top collapses to a single bar_lds.
// xg buffer split for in-place safety: step u's xq row dies after step u,
// so rows 0-11 overwrite in place (xqls); the C-fragment's quad-3 rows
// (12-15) are still live during steps 12-15 -> parity double-buffered side
// buffer sideb[2] (2x16KB). All new ops are compiler-visible LDS ops — no
// new inline-asm register liveness (the R12/R14 correctness-failure class).
// R15's second-chance prefetch removed (bench-neutral). R13 base otherwise:
// unified yst h-exchange, swizzled ystage loaded once per WG, proven R11
// prefetch schedule (flag u0, tie-test u2, issue u3, drain u10), batched
// sc0sc1 loads, chunk-end bulk y export / projection, 96 WGs = 3x32,
// CH=16, lgkm-only barriers, weights in registers (2 waves/SIMD pinned).

#define BATCH 128
#define TT    1024
#define HH    128
#define DD    64
#define NB    4
#define CH    16                // chunk steps
#define NG    32                // batch groups per layer
#define NCK   (TT / CH)
#define XBSTR (12 * 1024 + 8)   // xg rows 0-11 per batch (in-place)
#define SBSTR (4 * 1024 + 8)    // xg rows 12-15 per batch (parity dbuf)
#define YSTR  (CH * 256 + 32)   // h stage LDS bytes per batch (+32 pad)

typedef __attribute__((ext_vector_type(4))) float f32x4;
typedef __attribute__((ext_vector_type(8))) short bf16x8;
typedef __attribute__((ext_vector_type(4))) short bf16x4;
typedef __attribute__((ext_vector_type(4))) unsigned u32x4;

union U8 { unsigned long long q[2]; bf16x8 v; };

__device__ inline unsigned short f2bf(float f) {           // RNE
  unsigned u = __builtin_bit_cast(unsigned, f);
  u += 0x7FFFu + ((u >> 16) & 1u);
  return (unsigned short)(u >> 16);
}
__device__ inline float bf2f(unsigned short s) {
  return __builtin_bit_cast(float, (unsigned)s << 16);
}
__device__ inline float fsig(float x) {
  return __builtin_amdgcn_rcpf(1.f + __builtin_amdgcn_exp2f(-1.442695041f * x));
}
__device__ inline float ftanh(float x) {
  return 2.f * __builtin_amdgcn_rcpf(1.f + __builtin_amdgcn_exp2f(-2.885390082f * x)) - 1.f;
}
__device__ inline bf16x8 pack8(f32x4 a, f32x4 b) {
  bf16x8 r;
  r[0]=(short)f2bf(a[0]); r[1]=(short)f2bf(a[1]); r[2]=(short)f2bf(a[2]); r[3]=(short)f2bf(a[3]);
  r[4]=(short)f2bf(b[0]); r[5]=(short)f2bf(b[1]); r[6]=(short)f2bf(b[2]); r[7]=(short)f2bf(b[3]);
  return r;
}
// LDS-only barrier: does NOT drain vmcnt.
__device__ inline void bar_lds() {
  asm volatile("s_waitcnt lgkmcnt(0)\n\ts_barrier" ::: "memory");
}
__device__ inline void ystore8(unsigned short* p, unsigned long long v) {
  __hip_atomic_store((unsigned long long*)p, v, __ATOMIC_RELAXED, __HIP_MEMORY_SCOPE_AGENT);
}

__global__ void init_flags(int* f) { if (threadIdx.x < 64) f[threadIdx.x] = 0; }

// one M-tile of the chunk GEMM; expands in enclosing scope.
// MT = batch tile 0..3; SDST = side buffer for quad-3 rows (12-15).
#define GEMM_TILE(MT, SDST)                                                   \
  {                                                                           \
    const char* rb = ystage + (MT) * 4096 + l15 * 256;                        \
    f32x4 acc[4];                                                             \
    if (layer == 0) {                                                         \
      f32x4 x0 = *(const f32x4*)(rb + ((quad * 32) ^ swz_r));                 \
      f32x4 x1 = *(const f32x4*)(rb + ((quad * 32 + 16) ^ swz_r));            \
      f32x4 x2 = *(const f32x4*)(rb + ((128 + quad * 32) ^ swz_r));           \
      f32x4 x3 = *(const f32x4*)(rb + ((128 + quad * 32 + 16) ^ swz_r));      \
      bf16x8 af0 = pack8(x0, x1);                                             \
      bf16x8 af1 = pack8(x2, x3);                                             \
      _Pragma("unroll")                                                       \
      for (int q = 0; q < 4; ++q) acc[q] = __builtin_amdgcn_mfma_f32_16x16x32_bf16(af0, bwi[q][0], z4, 0, 0, 0); \
      _Pragma("unroll")                                                       \
      for (int q = 0; q < 4; ++q) acc[q] = __builtin_amdgcn_mfma_f32_16x16x32_bf16(af1, bwi[q][1], acc[q], 0, 0, 0); \
    } else {                                                                  \
      bf16x8 a4[4];                                                           \
      _Pragma("unroll")                                                       \
      for (int kc = 0; kc < 4; ++kc)                                          \
        a4[kc] = *(const bf16x8*)(rb + ((quad * 16 + kc * 64) ^ swz_r));      \
      _Pragma("unroll")                                                       \
      for (int q = 0; q < 4; ++q) acc[q] = __builtin_amdgcn_mfma_f32_16x16x32_bf16(a4[0], bwi[q][0], z4, 0, 0, 0); \
      _Pragma("unroll")                                                       \
      for (int kc = 1; kc < 4; ++kc)                                          \
        _Pragma("unroll")                                                     \
        for (int q = 0; q < 4; ++q) acc[q] = __builtin_amdgcn_mfma_f32_16x16x32_bf16(a4[kc], bwi[q][kc], acc[q], 0, 0, 0); \
    }                                                                         \
    char* wbase = (quad < 3) ? (xqls + (MT) * XBSTR + (quad * 4) * 1024 + j * 8) \
                             : ((SDST) + (MT) * SBSTR + j * 8);               \
    _Pragma("unroll")                                                         \
    for (int r = 0; r < 4; ++r) {                                             \
      bf16x4 o;                                                               \
      _Pragma("unroll")                                                       \
      for (int q = 0; q < 4; ++q) o[q] = (short)f2bf(acc[q][r] + bs[q]);      \
      *(bf16x4*)(wbase + r * 1024) = o;                                       \
    }                                                                         \
  }

__global__ __launch_bounds__(512) void lstm_fused(
    const float* __restrict__ x,
    const float* __restrict__ h0, const float* __restrict__ c0,
    const float* __restrict__ Wih0, const float* __restrict__ Whh0,
    const float* __restrict__ bih0, const float* __restrict__ bhh0,
    const float* __restrict__ Wih1, const float* __restrict__ Whh1,
    const float* __restrict__ bih1, const float* __restrict__ bhh1,
    const float* __restrict__ Wih2, const float* __restrict__ Whh2,
    const float* __restrict__ bih2, const float* __restrict__ bhh2,
    const float* __restrict__ Wout, const float* __restrict__ boutp,
    unsigned short* __restrict__ y0, unsigned short* __restrict__ y1,
    float* __restrict__ outp, float* __restrict__ hN, float* __restrict__ cN,
    int* __restrict__ flags)
{
  __shared__ __align__(16) char xqls[NB * XBSTR];     // xg rows 0-11 (in-place)
  __shared__ __align__(16) char sideb[2][NB * SBSTR]; // xg rows 12-15 (parity)
  __shared__ __align__(16) char yst[NB * YSTR];       // h stage [b][u][j]
  __shared__ __align__(16) char ystage[16384];        // A-tile stage, row-XOR-swizzled
  __shared__ int rdyf;                                 // prefetch-ready broadcast

  const int tid = threadIdx.x, wave = tid >> 6, lane = tid & 63;
  const int quad = lane >> 4, l15 = lane & 15;
  const int layer = blockIdx.x / NG, g = blockIdx.x % NG;
  const int bg0 = g * NB;
  const int gb = bg0 + quad;
  const int j = wave * 16 + l15;

  const float *Wih, *Whh, *bih, *bhh;
  const unsigned short* yin = nullptr;
  unsigned short* yout = nullptr;
  if (layer == 0)      { Wih = Wih0; Whh = Whh0; bih = bih0; bhh = bhh0; yout = y0; }
  else if (layer == 1) { Wih = Wih1; Whh = Whh1; bih = bih1; bhh = bhh1; yin = y0; yout = y1; }
  else                 { Wih = Wih2; Whh = Whh2; bih = bih2; bhh = bhh2; yin = y1; }
  const int Kin = (layer == 0) ? DD : HH;
  const int* fp = flags + (layer > 0 ? (layer - 1) * NG + g : 0);

  // Whh B-frags: tile n = q*128 + j, k = quad*8 + kc*32 + e
  bf16x8 bwh[4][4];
#pragma unroll
  for (int q = 0; q < 4; ++q)
#pragma unroll
    for (int kc = 0; kc < 4; ++kc) {
      const float* p = Whh + (size_t)(q * 128 + j) * HH + quad * 8 + kc * 32;
      bwh[q][kc] = pack8(*(const f32x4*)p, *(const f32x4*)(p + 4));
    }
  // Wih B-frags (K = 64 or 128)
  bf16x8 bwi[4][4];
#pragma unroll
  for (int q = 0; q < 4; ++q)
    for (int kc = 0; kc < Kin / 32; ++kc) {
      const float* p = Wih + (size_t)(q * 128 + j) * Kin + quad * 8 + kc * 32;
      bwi[q][kc] = pack8(*(const f32x4*)p, *(const f32x4*)(p + 4));
    }
  float bs[4];
#pragma unroll
  for (int q = 0; q < 4; ++q) bs[q] = bih[q * 128 + j] + bhh[q * 128 + j];

  // A-tile stage geometry: row byte-length 256 for BOTH y (128 bf16) and
  // x (64 f32). Writer: thread covers 32B. Swizzle: byte ^= (row&7)<<4.
  const int stg_b = tid >> 7, stg_u = (tid >> 3) & 15, stg_p = tid & 7;
  const int swz_w = (stg_u & 7) << 4;
  const int wr0 = stg_b * 4096 + stg_u * 256 + ((stg_p * 32) ^ swz_w);
  const int wr1 = stg_b * 4096 + stg_u * 256 + ((stg_p * 32 + 16) ^ swz_w);
  const int swz_r = (l15 & 7) << 4;

  const float* h0l = h0 + (size_t)layer * BATCH * HH;
  const float* c0l = c0 + (size_t)layer * BATCH * HH;
  // seed h0 into yst row 15 (step 0 reads row (0+15)&15 = 15)
  *(unsigned short*)(yst + quad * YSTR + 15 * 256 + j * 2) = f2bf(h0l[(size_t)gb * HH + j]);
  float cc = c0l[(size_t)gb * HH + j];

  // projection weights (layer 2): Wout[lg*16 .. lg*16+15] per lane group
  f32x4 wvp0 = {0,0,0,0}, wvp1 = {0,0,0,0}, wvp2 = {0,0,0,0}, wvp3 = {0,0,0,0};
  float ob = 0.f;
  if (layer == 2) {
    const float* wp = Wout + (lane & 7) * 16;
    wvp0 = *(const f32x4*)(wp + 0);
    wvp1 = *(const f32x4*)(wp + 4);
    wvp2 = *(const f32x4*)(wp + 8);
    wvp3 = *(const f32x4*)(wp + 12);
    ob = boutp[0];
  }

  __syncthreads();

  const f32x4 z4 = {0.f, 0.f, 0.f, 0.f};
  float hv = 0.f;
  const int yst_w = quad * YSTR + j * 2;            // + u*256 per step
  const char* abase0 = yst + (l15 >> 2) * YSTR + quad * 16;  // + row*256, +kc*64
  int havepf = 0;   // also means: xg for the NEXT chunk already spread-computed

  for (int ck = 0; ck < NCK; ++ck) {
    int t0 = ck * CH;
    char* sider = sideb[ck & 1];          // xg rows 12-15 of CURRENT chunk
    char* sidew = sideb[(ck & 1) ^ 1];    // xg rows 12-15 of NEXT chunk

    // ---- chunk top ----
    if (!havepf) {
      // fallback / first / last chunk: sync, stage A-tile, full GEMM now
      if (layer > 0) {
        if (tid == 0) {
          while (__hip_atomic_load(fp, __ATOMIC_ACQUIRE, __HIP_MEMORY_SCOPE_AGENT) <= ck)
            __builtin_amdgcn_s_sleep(1);
        }
        __syncthreads();
      }
      u32x4 s0v, s1v;
      if (layer == 0) {
        const float* gp = x + ((size_t)(bg0 + stg_b) * TT + t0 + stg_u) * DD + stg_p * 8;
        asm volatile("global_load_dwordx4 %0, %2, off\n\t"
                     "global_load_dwordx4 %1, %2, off offset:16\n\t"
                     "s_waitcnt vmcnt(0)"
                     : "=&v"(s0v), "=&v"(s1v) : "v"(gp) : "memory");
      } else {
        const unsigned short* gp = yin + ((size_t)(bg0 + stg_b) * TT + t0 + stg_u) * HH + stg_p * 16;
        asm volatile("global_load_dwordx4 %0, %2, off sc0 sc1\n\t"
                     "global_load_dwordx4 %1, %2, off offset:16 sc0 sc1\n\t"
                     "s_waitcnt vmcnt(0)"
                     : "=&v"(s0v), "=&v"(s1v) : "v"(gp) : "memory");
      }
      *(u32x4*)(ystage + wr0) = s0v;
      *(u32x4*)(ystage + wr1) = s1v;
      bar_lds();
#pragma unroll
      for (int mt = 0; mt < 4; ++mt) GEMM_TILE(mt, sider);
      bar_lds();
    } else {
      // steady state: xg already computed by last chunk's spread-GEMM.
      // Single barrier orders epilogue yst reads vs this chunk's writes.
      bar_lds();
    }

    // ---- CH recurrence steps + hidden prefetch + spread-GEMM ----
    unsigned fvp = 0;
    u32x4 pf0, pf1;
#pragma unroll
    for (int u = 0; u < CH; ++u) {
      // A-frags directly from yst row (u+15)&15 (4-lane broadcast reads)
      const char* ab = abase0 + (((u + 15) & 15) * 256);
      bf16x8 a0 = *(const bf16x8*)(ab);
      bf16x8 a1 = *(const bf16x8*)(ab + 64);
      bf16x8 a2 = *(const bf16x8*)(ab + 128);
      bf16x8 a3 = *(const bf16x8*)(ab + 192);
      const char* xb = (u < 12) ? (xqls + quad * XBSTR + u * 1024)
                                : (sider + quad * SBSTR + (u - 12) * 1024);
      bf16x4 xq4 = *(const bf16x4*)(xb + j * 8);

      f32x4 c01[4], c23[4];
#pragma unroll
      for (int q = 0; q < 4; ++q) c01[q] = __builtin_amdgcn_mfma_f32_16x16x32_bf16(a0, bwh[q][0], z4, 0, 0, 0);
#pragma unroll
      for (int q = 0; q < 4; ++q) c23[q] = __builtin_amdgcn_mfma_f32_16x16x32_bf16(a2, bwh[q][2], z4, 0, 0, 0);
#pragma unroll
      for (int q = 0; q < 4; ++q) c01[q] = __builtin_amdgcn_mfma_f32_16x16x32_bf16(a1, bwh[q][1], c01[q], 0, 0, 0);
#pragma unroll
      for (int q = 0; q < 4; ++q) c23[q] = __builtin_amdgcn_mfma_f32_16x16x32_bf16(a3, bwh[q][3], c23[q], 0, 0, 0);

      float gi = fsig(c01[0][0] + c23[0][0] + bf2f((unsigned short)xq4[0]));
      float gf = fsig(c01[1][0] + c23[1][0] + bf2f((unsigned short)xq4[1]));
      float gg = ftanh(c01[2][0] + c23[2][0] + bf2f((unsigned short)xq4[2]));
      float go = fsig(c01[3][0] + c23[3][0] + bf2f((unsigned short)xq4[3]));
      cc = gf * cc + gi * gg;
      hv = go * ftanh(cc);
      unsigned short hb = f2bf(hv);
      *(unsigned short*)(yst + yst_w + u * 256) = hb;   // single h store

      // ---- prefetch machinery (R11/R13 schedule, bench-proven) ----
      if (u == 0 && layer > 0 && ck + 1 < NCK) {
        asm volatile("global_load_dword %0, %1, off sc0 sc1"
                     : "=&v"(fvp) : "v"(fp) : "memory");
      }
      if (u == 2 && layer > 0 && ck + 1 < NCK) {
        // rule-#18: value tied THROUGH the waitcnt + sched fence
        asm volatile("s_waitcnt vmcnt(0)" : "+v"(fvp) :: "memory");
        __builtin_amdgcn_sched_barrier(0);
        int rdy = __any((int)fvp > ck + 1) ? 1 : 0;     // producer >= ck+2
        if (tid == 0) rdyf = rdy;                       // visible after bar_lds
      }
      if (u == 3) {
        havepf = 0;
        if (ck + 1 < NCK) {
          if (layer == 0) {
            const float* gp = x + ((size_t)(bg0 + stg_b) * TT + t0 + CH + stg_u) * DD + stg_p * 8;
            asm volatile("global_load_dwordx4 %0, %2, off\n\t"
                         "global_load_dwordx4 %1, %2, off offset:16"
                         : "=&v"(pf0), "=&v"(pf1) : "v"(gp) : "memory");
            havepf = 1;
          } else if (rdyf) {
            const unsigned short* gp = yin + ((size_t)(bg0 + stg_b) * TT + t0 + CH + stg_u) * HH + stg_p * 16;
            asm volatile("global_load_dwordx4 %0, %2, off sc0 sc1\n\t"
                         "global_load_dwordx4 %1, %2, off offset:16 sc0 sc1"
                         : "=&v"(pf0), "=&v"(pf1) : "v"(gp) : "memory");
            havepf = 1;
          }
        }
      }
      if (u == 10 && havepf) {
        asm volatile("s_waitcnt vmcnt(0)" ::: "memory"); // prefetch loads done
        __builtin_amdgcn_sched_barrier(0);               // rule-#18 fence
        *(u32x4*)(ystage + wr0) = pf0;                   // ordered ds_writes
        *(u32x4*)(ystage + wr1) = pf1;
      }

      // ---- spread-GEMM: one M-tile of NEXT chunk's xg per step 12-15 ----
      // ystage(ck+1) visible since u==10's bar_lds. Writes: rows 0-11 in
      // place (dead after their step), rows 12-15 to sidew (parity dbuf).
      // Independent of the recurrence chain -> fills per-step stalls.
      if (u >= 12 && havepf) {
        GEMM_TILE(u - 12, sidew);
      }
      bar_lds();
    }

    // ---- chunk epilogue ----
    if (layer < 2) {
      // bulk y export: 16 KB stage -> global via wide agent-scope stores
#pragma unroll
      for (int s = 0; s < 2; ++s) {
        int seg = tid + s * 512;
        int b = seg >> 8, u = (seg >> 4) & 15, part = seg & 15;
        U8 v; v.v = *(const bf16x8*)(yst + b * YSTR + u * 256 + part * 16);
        size_t di = ((size_t)(bg0 + b) * TT + t0 + u) * HH + part * 8;
        ystore8(yout + di, v.q[0]);
        ystore8(yout + di + 4, v.q[1]);
      }
      asm volatile("s_waitcnt vmcnt(0)" ::: "memory");
      __syncthreads();
      if (tid == 0)
        __hip_atomic_store(flags + layer * NG + g, ck + 1,
                           __ATOMIC_RELAXED, __HIP_MEMORY_SCOPE_AGENT);
    } else {
      // projection: 64 outputs (4 b x 16 u), 8 lanes per output
      int og = lane >> 3, lg = lane & 7;
      int o = wave * 8 + og;
      int b = o >> 4, u = o & 15;
      const char* sp = yst + b * YSTR + u * 256 + lg * 32;
      bf16x8 ha = *(const bf16x8*)sp;
      bf16x8 hbv = *(const bf16x8*)(sp + 16);
      float s = 0.f;
#pragma unroll
      for (int e = 0; e < 4; ++e) s += bf2f((unsigned short)ha[e]) * wvp0[e];
#pragma unroll
      for (int e = 0; e < 4; ++e) s += bf2f((unsigned short)ha[e + 4]) * wvp1[e];
#pragma unroll
      for (int e = 0; e < 4; ++e) s += bf2f((unsigned short)hbv[e]) * wvp2[e];
#pragma unroll
      for (int e = 0; e < 4; ++e) s += bf2f((unsigned short)hbv[e + 4]) * wvp3[e];
      s += __shfl_xor(s, 1);
      s += __shfl_xor(s, 2);
      s += __shfl_xor(s, 4);
      if (lg == 0) outp[(size_t)(bg0 + b) * TT + t0 + u] = fmaxf(s + ob, 0.f);
      // yst reads ordered vs next chunk's step writes by the chunk-top
      // bar_lds.
    }
  }

  float* hNl = hN + (size_t)layer * BATCH * HH;
  float* cNl = cN + (size_t)layer * BATCH * HH;
  hNl[(size_t)gb * HH + j] = hv;
  cNl[(size_t)gb * HH + j] = cc;
}

// ---------------- launch ----------------
extern "C" void kernel_launch(void* const* d_in, const int* in_sizes, int n_in,
                              void* d_out, int out_size, void* d_ws, size_t ws_size,
                              hipStream_t stream) {
  const float* x  = (const float*)d_in[0];
  const float* h0 = (const float*)d_in[1];
  const float* c0 = (const float*)d_in[2];
  const float* Wih[3] = {(const float*)d_in[3], (const float*)d_in[7],  (const float*)d_in[11]};
  const float* Whh[3] = {(const float*)d_in[4], (const float*)d_in[8],  (const float*)d_in[12]};
  const float* bih[3] = {(const float*)d_in[5], (const float*)d_in[9],  (const float*)d_in[13]};
  const float* bhh[3] = {(const float*)d_in[6], (const float*)d_in[10], (const float*)d_in[14]};
  const float* Wout = (const float*)d_in[15];
  const float* bout = (const float*)d_in[16];

  float* outp = (float*)d_out;                 // [B][T]
  float* hN = outp + BATCH * TT;               // [L][B][H]
  float* cN = hN + 3 * BATCH * HH;

  char* ws = (char*)d_ws;
  int* flags = (int*)ws;                                            // 64 ints
  unsigned short* y0 = (unsigned short*)(ws + 4096);                // 32 MB
  unsigned short* y1 = (unsigned short*)(ws + 4096 + (size_t)BATCH * TT * HH * 2);

  init_flags<<<1, 64, 0, stream>>>(flags);
  lstm_fused<<<3 * NG, 512, 0, stream>>>(
      x, h0, c0,
      Wih[0], Whh[0], bih[0], bhh[0],
      Wih[1], Whh[1], bih[1], bhh[1],
      Wih[2], Whh[2], bih[2], bhh[2],
      Wout, bout, y0, y1, outp, hN, cN, flags);
}

// Round 11
// 1113.313 us; speedup vs baseline: 1.4317x; 1.4317x over previous
//
#include <hip/hip_runtime.h>

// LSTM B=128,T=1024,H=128,D=64,L=3 — fused, layer-pipelined, R17.
// R17 = exact revert to R13 (best verified: 1065us). R16's spread-GEMM
// (GEMM tiles relocated into steps 12-15) regressed 45%: VGPR fell 120->108
// while steps gained 32+ live regs -> allocator spilled to scratch inside
// the barrier-locked step loop (~800cy/access). Lesson (with R12/R14): the
// step loop runs at the register-budget edge; ANY added live state inside
// it spills. The weight fragments (128 regs) pin the design to 2 waves/SIMD
// and forbid both >=4-wave occupancy (R14) and in-step register-hungry
// overlap (R16). 1065us is this structure's measured floor: pacing period
// 16.1us/chunk x 64 chunks + pipeline fill, dominated by the serial
// barrier-locked recurrence.
// Structure: 96 WGs = 3 layers x 32 batch-groups (NB=4, WG=512, CH=16).
// - Cross-layer y exchange via IF$ (sc0sc1 / relaxed agent atomics),
//   ordered by vmcnt(0)+flag; per-chunk producer flags.
// - A-tile (x or y) prefetched during steps (flag u0, tie-test u2 with
//   rule-#18 "+v"-through-waitcnt + sched_barrier, issue u3, drain u10)
//   into a 16KB row-XOR-swizzled LDS stage loaded once per WG.
// - Chunk-top GEMM reads the stage; steady state skips poll/sync/wait.
// - Unified yst h-exchange: single ds_write_b16/step serves recurrence
//   A-frags (4-lane broadcast reads), y export, and projection.
// - Chunk-end bulk y export (wide agent stores) / layer-2 projection.

#define BATCH 128
#define TT    1024
#define HH    128
#define DD    64
#define NB    4
#define CH    16                // chunk steps
#define NG    32                // batch groups per layer
#define NCK   (TT / CH)
#define BSTR  (CH * 1024 + 8)   // xg LDS bytes per batch
#define YSTR  (CH * 256 + 32)   // y/h stage LDS bytes per batch (+32 pad)

typedef __attribute__((ext_vector_type(4))) float f32x4;
typedef __attribute__((ext_vector_type(8))) short bf16x8;
typedef __attribute__((ext_vector_type(4))) short bf16x4;
typedef __attribute__((ext_vector_type(4))) unsigned u32x4;

union U8 { unsigned long long q[2]; bf16x8 v; };

__device__ inline unsigned short f2bf(float f) {           // RNE
  unsigned u = __builtin_bit_cast(unsigned, f);
  u += 0x7FFFu + ((u >> 16) & 1u);
  return (unsigned short)(u >> 16);
}
__device__ inline float bf2f(unsigned short s) {
  return __builtin_bit_cast(float, (unsigned)s << 16);
}
__device__ inline float fsig(float x) {
  return __builtin_amdgcn_rcpf(1.f + __builtin_amdgcn_exp2f(-1.442695041f * x));
}
__device__ inline float ftanh(float x) {
  return 2.f * __builtin_amdgcn_rcpf(1.f + __builtin_amdgcn_exp2f(-2.885390082f * x)) - 1.f;
}
__device__ inline bf16x8 pack8(f32x4 a, f32x4 b) {
  bf16x8 r;
  r[0]=(short)f2bf(a[0]); r[1]=(short)f2bf(a[1]); r[2]=(short)f2bf(a[2]); r[3]=(short)f2bf(a[3]);
  r[4]=(short)f2bf(b[0]); r[5]=(short)f2bf(b[1]); r[6]=(short)f2bf(b[2]); r[7]=(short)f2bf(b[3]);
  return r;
}
// LDS-only barrier: does NOT drain vmcnt.
__device__ inline void bar_lds() {
  asm volatile("s_waitcnt lgkmcnt(0)\n\ts_barrier" ::: "memory");
}
__device__ inline void ystore8(unsigned short* p, unsigned long long v) {
  __hip_atomic_store((unsigned long long*)p, v, __ATOMIC_RELAXED, __HIP_MEMORY_SCOPE_AGENT);
}

__global__ void init_flags(int* f) { if (threadIdx.x < 64) f[threadIdx.x] = 0; }

__global__ __launch_bounds__(512) void lstm_fused(
    const float* __restrict__ x,
    const float* __restrict__ h0, const float* __restrict__ c0,
    const float* __restrict__ Wih0, const float* __restrict__ Whh0,
    const float* __restrict__ bih0, const float* __restrict__ bhh0,
    const float* __restrict__ Wih1, const float* __restrict__ Whh1,
    const float* __restrict__ bih1, const float* __restrict__ bhh1,
    const float* __restrict__ Wih2, const float* __restrict__ Whh2,
    const float* __restrict__ bih2, const float* __restrict__ bhh2,
    const float* __restrict__ Wout, const float* __restrict__ boutp,
    unsigned short* __restrict__ y0, unsigned short* __restrict__ y1,
    float* __restrict__ outp, float* __restrict__ hN, float* __restrict__ cN,
    int* __restrict__ flags)
{
  __shared__ __align__(16) char xqls[NB * BSTR];   // xg chunk [b][t][j][gate]
  __shared__ __align__(16) char yst[NB * YSTR];    // h stage [b][u][j] — exchange + export + proj
  __shared__ __align__(16) char ystage[16384];     // A-tile stage [b][row][256B], row-XOR-swizzled
  __shared__ int rdyf;                              // prefetch-ready broadcast

  const int tid = threadIdx.x, wave = tid >> 6, lane = tid & 63;
  const int quad = lane >> 4, l15 = lane & 15;
  const int layer = blockIdx.x / NG, g = blockIdx.x % NG;
  const int bg0 = g * NB;
  const int gb = bg0 + quad;
  const int j = wave * 16 + l15;

  const float *Wih, *Whh, *bih, *bhh;
  const unsigned short* yin = nullptr;
  unsigned short* yout = nullptr;
  if (layer == 0)      { Wih = Wih0; Whh = Whh0; bih = bih0; bhh = bhh0; yout = y0; }
  else if (layer == 1) { Wih = Wih1; Whh = Whh1; bih = bih1; bhh = bhh1; yin = y0; yout = y1; }
  else                 { Wih = Wih2; Whh = Whh2; bih = bih2; bhh = bhh2; yin = y1; }
  const int Kin = (layer == 0) ? DD : HH;
  const int* fp = flags + (layer > 0 ? (layer - 1) * NG + g : 0);

  // Whh B-frags: tile n = q*128 + j, k = quad*8 + kc*32 + e
  bf16x8 bwh[4][4];
#pragma unroll
  for (int q = 0; q < 4; ++q)
#pragma unroll
    for (int kc = 0; kc < 4; ++kc) {
      const float* p = Whh + (size_t)(q * 128 + j) * HH + quad * 8 + kc * 32;
      bwh[q][kc] = pack8(*(const f32x4*)p, *(const f32x4*)(p + 4));
    }
  // Wih B-frags (K = 64 or 128)
  bf16x8 bwi[4][4];
#pragma unroll
  for (int q = 0; q < 4; ++q)
    for (int kc = 0; kc < Kin / 32; ++kc) {
      const float* p = Wih + (size_t)(q * 128 + j) * Kin + quad * 8 + kc * 32;
      bwi[q][kc] = pack8(*(const f32x4*)p, *(const f32x4*)(p + 4));
    }
  float bs[4];
#pragma unroll
  for (int q = 0; q < 4; ++q) bs[q] = bih[q * 128 + j] + bhh[q * 128 + j];

  // A-tile stage geometry: row byte-length 256 for BOTH y (128 bf16) and
  // x (64 f32). Writer: thread covers 32B. Swizzle: byte ^= (row&7)<<4.
  const int stg_b = tid >> 7, stg_u = (tid >> 3) & 15, stg_p = tid & 7;
  const int swz_w = (stg_u & 7) << 4;
  const int wr0 = stg_b * 4096 + stg_u * 256 + ((stg_p * 32) ^ swz_w);
  const int wr1 = stg_b * 4096 + stg_u * 256 + ((stg_p * 32 + 16) ^ swz_w);
  const int swz_r = (l15 & 7) << 4;

  const float* h0l = h0 + (size_t)layer * BATCH * HH;
  const float* c0l = c0 + (size_t)layer * BATCH * HH;
  // seed h0 into yst row 15 (step 0 reads row (0+15)&15 = 15)
  *(unsigned short*)(yst + quad * YSTR + 15 * 256 + j * 2) = f2bf(h0l[(size_t)gb * HH + j]);
  float cc = c0l[(size_t)gb * HH + j];

  // projection weights (layer 2): Wout[lg*16 .. lg*16+15] per lane group
  f32x4 wvp0 = {0,0,0,0}, wvp1 = {0,0,0,0}, wvp2 = {0,0,0,0}, wvp3 = {0,0,0,0};
  float ob = 0.f;
  if (layer == 2) {
    const float* wp = Wout + (lane & 7) * 16;
    wvp0 = *(const f32x4*)(wp + 0);
    wvp1 = *(const f32x4*)(wp + 4);
    wvp2 = *(const f32x4*)(wp + 8);
    wvp3 = *(const f32x4*)(wp + 12);
    ob = boutp[0];
  }

  __syncthreads();

  const f32x4 z4 = {0.f, 0.f, 0.f, 0.f};
  float hv = 0.f;
  const int yst_w = quad * YSTR + j * 2;            // + u*256 per step
  const char* abase0 = yst + (l15 >> 2) * YSTR + quad * 16;  // + row*256, +kc*64
  int havepf = 0;

  for (int ck = 0; ck < NCK; ++ck) {
    int t0 = ck * CH;

    // ---- ensure ystage holds this chunk's A-tile ----
    if (!havepf) {
      if (layer > 0) {
        if (tid == 0) {
          while (__hip_atomic_load(fp, __ATOMIC_ACQUIRE, __HIP_MEMORY_SCOPE_AGENT) <= ck)
            __builtin_amdgcn_s_sleep(1);
        }
        __syncthreads();
      }
      u32x4 s0v, s1v;
      if (layer == 0) {
        const float* gp = x + ((size_t)(bg0 + stg_b) * TT + t0 + stg_u) * DD + stg_p * 8;
        asm volatile("global_load_dwordx4 %0, %2, off\n\t"
                     "global_load_dwordx4 %1, %2, off offset:16\n\t"
                     "s_waitcnt vmcnt(0)"
                     : "=&v"(s0v), "=&v"(s1v) : "v"(gp) : "memory");
      } else {
        const unsigned short* gp = yin + ((size_t)(bg0 + stg_b) * TT + t0 + stg_u) * HH + stg_p * 16;
        asm volatile("global_load_dwordx4 %0, %2, off sc0 sc1\n\t"
                     "global_load_dwordx4 %1, %2, off offset:16 sc0 sc1\n\t"
                     "s_waitcnt vmcnt(0)"
                     : "=&v"(s0v), "=&v"(s1v) : "v"(gp) : "memory");
      }
      *(u32x4*)(ystage + wr0) = s0v;
      *(u32x4*)(ystage + wr1) = s1v;
      bar_lds();
    }
    // (prefetched path: stage writes ordered by step barriers — go
    //  straight to GEMM.)

    // ---- fused chunk GEMM from LDS stage: 4 M-tiles ----
    if (layer == 0) {
#pragma unroll
      for (int mt = 0; mt < 4; ++mt) {
        const char* rb = ystage + mt * 4096 + l15 * 256;
        f32x4 x0 = *(const f32x4*)(rb + ((quad * 32) ^ swz_r));
        f32x4 x1 = *(const f32x4*)(rb + ((quad * 32 + 16) ^ swz_r));
        f32x4 x2 = *(const f32x4*)(rb + ((128 + quad * 32) ^ swz_r));
        f32x4 x3 = *(const f32x4*)(rb + ((128 + quad * 32 + 16) ^ swz_r));
        bf16x8 af0 = pack8(x0, x1);
        bf16x8 af1 = pack8(x2, x3);
        f32x4 acc[4];
#pragma unroll
        for (int q = 0; q < 4; ++q) acc[q] = __builtin_amdgcn_mfma_f32_16x16x32_bf16(af0, bwi[q][0], z4, 0, 0, 0);
#pragma unroll
        for (int q = 0; q < 4; ++q) acc[q] = __builtin_amdgcn_mfma_f32_16x16x32_bf16(af1, bwi[q][1], acc[q], 0, 0, 0);
        char* base = xqls + mt * BSTR + (quad * 4) * 1024 + j * 8;
#pragma unroll
        for (int r = 0; r < 4; ++r) {
          bf16x4 o;
#pragma unroll
          for (int q = 0; q < 4; ++q) o[q] = (short)f2bf(acc[q][r] + bs[q]);
          *(bf16x4*)(base + r * 1024) = o;
        }
      }
    } else {
#pragma unroll
      for (int mt = 0; mt < 4; ++mt) {
        const char* rb = ystage + mt * 4096 + l15 * 256;
        bf16x8 a4[4];
#pragma unroll
        for (int kc = 0; kc < 4; ++kc)
          a4[kc] = *(const bf16x8*)(rb + ((quad * 16 + kc * 64) ^ swz_r));
        f32x4 acc[4];
#pragma unroll
        for (int q = 0; q < 4; ++q) acc[q] = __builtin_amdgcn_mfma_f32_16x16x32_bf16(a4[0], bwi[q][0], z4, 0, 0, 0);
#pragma unroll
        for (int kc = 1; kc < 4; ++kc)
#pragma unroll
          for (int q = 0; q < 4; ++q) acc[q] = __builtin_amdgcn_mfma_f32_16x16x32_bf16(a4[kc], bwi[q][kc], acc[q], 0, 0, 0);
        char* base = xqls + mt * BSTR + (quad * 4) * 1024 + j * 8;
#pragma unroll
        for (int r = 0; r < 4; ++r) {
          bf16x4 o;
#pragma unroll
          for (int q = 0; q < 4; ++q) o[q] = (short)f2bf(acc[q][r] + bs[q]);
          *(bf16x4*)(base + r * 1024) = o;
        }
      }
    }
    bar_lds();

    // ---- CH recurrence steps (uniform body) + hidden prefetch ----
    unsigned fvp = 0;
    u32x4 pf0, pf1;
#pragma unroll
    for (int u = 0; u < CH; ++u) {
      // A-frags directly from yst row (u+15)&15 (4-lane broadcast reads)
      const char* ab = abase0 + (((u + 15) & 15) * 256);
      bf16x8 a0 = *(const bf16x8*)(ab);
      bf16x8 a1 = *(const bf16x8*)(ab + 64);
      bf16x8 a2 = *(const bf16x8*)(ab + 128);
      bf16x8 a3 = *(const bf16x8*)(ab + 192);
      bf16x4 xq4 = *(const bf16x4*)(xqls + quad * BSTR + u * 1024 + j * 8);

      f32x4 c01[4], c23[4];
#pragma unroll
      for (int q = 0; q < 4; ++q) c01[q] = __builtin_amdgcn_mfma_f32_16x16x32_bf16(a0, bwh[q][0], z4, 0, 0, 0);
#pragma unroll
      for (int q = 0; q < 4; ++q) c23[q] = __builtin_amdgcn_mfma_f32_16x16x32_bf16(a2, bwh[q][2], z4, 0, 0, 0);
#pragma unroll
      for (int q = 0; q < 4; ++q) c01[q] = __builtin_amdgcn_mfma_f32_16x16x32_bf16(a1, bwh[q][1], c01[q], 0, 0, 0);
#pragma unroll
      for (int q = 0; q < 4; ++q) c23[q] = __builtin_amdgcn_mfma_f32_16x16x32_bf16(a3, bwh[q][3], c23[q], 0, 0, 0);

      float gi = fsig(c01[0][0] + c23[0][0] + bf2f((unsigned short)xq4[0]));
      float gf = fsig(c01[1][0] + c23[1][0] + bf2f((unsigned short)xq4[1]));
      float gg = ftanh(c01[2][0] + c23[2][0] + bf2f((unsigned short)xq4[2]));
      float go = fsig(c01[3][0] + c23[3][0] + bf2f((unsigned short)xq4[3]));
      cc = gf * cc + gi * gg;
      hv = go * ftanh(cc);
      unsigned short hb = f2bf(hv);
      *(unsigned short*)(yst + yst_w + u * 256) = hb;   // single h store (exchange+stage)

      // ---- prefetch machinery (R11 schedule, bench-proven) ----
      if (u == 0 && layer > 0 && ck + 1 < NCK) {
        asm volatile("global_load_dword %0, %1, off sc0 sc1"
                     : "=&v"(fvp) : "v"(fp) : "memory");
      }
      if (u == 2 && layer > 0 && ck + 1 < NCK) {
        // rule-#18: value tied THROUGH the waitcnt + sched fence
        asm volatile("s_waitcnt vmcnt(0)" : "+v"(fvp) :: "memory");
        __builtin_amdgcn_sched_barrier(0);
        int rdy = __any((int)fvp > ck + 1) ? 1 : 0;     // producer >= ck+2
        if (tid == 0) rdyf = rdy;                       // visible after bar_lds
      }
      if (u == 3) {
        havepf = 0;
        if (ck + 1 < NCK) {
          if (layer == 0) {
            const float* gp = x + ((size_t)(bg0 + stg_b) * TT + t0 + CH + stg_u) * DD + stg_p * 8;
            asm volatile("global_load_dwordx4 %0, %2, off\n\t"
                         "global_load_dwordx4 %1, %2, off offset:16"
                         : "=&v"(pf0), "=&v"(pf1) : "v"(gp) : "memory");
            havepf = 1;
          } else if (rdyf) {
            const unsigned short* gp = yin + ((size_t)(bg0 + stg_b) * TT + t0 + CH + stg_u) * HH + stg_p * 16;
            asm volatile("global_load_dwordx4 %0, %2, off sc0 sc1\n\t"
                         "global_load_dwordx4 %1, %2, off offset:16 sc0 sc1"
                         : "=&v"(pf0), "=&v"(pf1) : "v"(gp) : "memory");
            havepf = 1;
          }
        }
      }
      if (u == 10 && havepf) {
        asm volatile("s_waitcnt vmcnt(0)" ::: "memory"); // prefetch loads done
        __builtin_amdgcn_sched_barrier(0);               // rule-#18 fence
        *(u32x4*)(ystage + wr0) = pf0;                   // ordered ds_writes
        *(u32x4*)(ystage + wr1) = pf1;
      }
      bar_lds();
    }

    // ---- chunk epilogue ----
    if (layer < 2) {
      // bulk y export: 16 KB stage -> global via wide agent-scope stores
#pragma unroll
      for (int s = 0; s < 2; ++s) {
        int seg = tid + s * 512;
        int b = seg >> 8, u = (seg >> 4) & 15, part = seg & 15;
        U8 v; v.v = *(const bf16x8*)(yst + b * YSTR + u * 256 + part * 16);
        size_t di = ((size_t)(bg0 + b) * TT + t0 + u) * HH + part * 8;
        ystore8(yout + di, v.q[0]);
        ystore8(yout + di + 4, v.q[1]);
      }
      asm volatile("s_waitcnt vmcnt(0)" ::: "memory");
      __syncthreads();
      if (tid == 0)
        __hip_atomic_store(flags + layer * NG + g, ck + 1,
                           __ATOMIC_RELAXED, __HIP_MEMORY_SCOPE_AGENT);
    } else {
      // projection: 64 outputs (4 b x 16 u), 8 lanes per output
      int og = lane >> 3, lg = lane & 7;
      int o = wave * 8 + og;
      int b = o >> 4, u = o & 15;
      const char* sp = yst + b * YSTR + u * 256 + lg * 32;
      bf16x8 ha = *(const bf16x8*)sp;
      bf16x8 hbv = *(const bf16x8*)(sp + 16);
      float s = 0.f;
#pragma unroll
      for (int e = 0; e < 4; ++e) s += bf2f((unsigned short)ha[e]) * wvp0[e];
#pragma unroll
      for (int e = 0; e < 4; ++e) s += bf2f((unsigned short)ha[e + 4]) * wvp1[e];
#pragma unroll
      for (int e = 0; e < 4; ++e) s += bf2f((unsigned short)hbv[e]) * wvp2[e];
#pragma unroll
      for (int e = 0; e < 4; ++e) s += bf2f((unsigned short)hbv[e + 4]) * wvp3[e];
      s += __shfl_xor(s, 1);
      s += __shfl_xor(s, 2);
      s += __shfl_xor(s, 4);
      if (lg == 0) outp[(size_t)(bg0 + b) * TT + t0 + u] = fmaxf(s + ob, 0.f);
      // yst reads drain at the next GEMM-phase bar_lds before step-0
      // overwrites yst; row 15 (read by step 0) is written only at step 15.
    }
  }

  float* hNl = hN + (size_t)layer * BATCH * HH;
  float* cNl = cN + (size_t)layer * BATCH * HH;
  hNl[(size_t)gb * HH + j] = hv;
  cNl[(size_t)gb * HH + j] = cc;
}

// ---------------- launch ----------------
extern "C" void kernel_launch(void* const* d_in, const int* in_sizes, int n_in,
                              void* d_out, int out_size, void* d_ws, size_t ws_size,
                              hipStream_t stream) {
  const float* x  = (const float*)d_in[0];
  const float* h0 = (const float*)d_in[1];
  const float* c0 = (const float*)d_in[2];
  const float* Wih[3] = {(const float*)d_in[3], (const float*)d_in[7],  (const float*)d_in[11]};
  const float* Whh[3] = {(const float*)d_in[4], (const float*)d_in[8],  (const float*)d_in[12]};
  const float* bih[3] = {(const float*)d_in[5], (const float*)d_in[9],  (const float*)d_in[13]};
  const float* bhh[3] = {(const float*)d_in[6], (const float*)d_in[10], (const float*)d_in[14]};
  const float* Wout = (const float*)d_in[15];
  const float* bout = (const float*)d_in[16];

  float* outp = (float*)d_out;                 // [B][T]
  float* hN = outp + BATCH * TT;               // [L][B][H]
  float* cN = hN + 3 * BATCH * HH;

  char* ws = (char*)d_ws;
  int* flags = (int*)ws;                                            // 64 ints
  unsigned short* y0 = (unsigned short*)(ws + 4096);                // 32 MB
  unsigned short* y1 = (unsigned short*)(ws + 4096 + (size_t)BATCH * TT * HH * 2);

  init_flags<<<1, 64, 0, stream>>>(flags);
  lstm_fused<<<3 * NG, 512, 0, stream>>>(
      x, h0, c0,
      Wih[0], Whh[0], bih[0], bhh[0],
      Wih[1], Whh[1], bih[1], bhh[1],
      Wih[2], Whh[2], bih[2], bhh[2],
      Wout, bout, y0, y1, outp, hN, cN, flags);
}

// Round 12
// 865.041 us; speedup vs baseline: 1.8426x; 1.2870x over previous
//
#include <hip/hip_runtime.h>

// LSTM B=128,T=1024,H=128,D=64,L=3 — fused, layer-pipelined, R18.
// R18 change: HALVE the chunk count at constant LDS — CH 16->32, NB 4->2
// (NG 64 groups/layer, grid 192, still 1 WG/CU, 8 waves, 2 waves/SIMD).
// Rationale: counters are latency-bound, and the pacing layers' 16.1us
// chunk period vs layer 0's 10.9 is dominated by PER-CHUNK serial overhead
// (exposed chunk-top GEMM ~0.5-1us [R16 proved it can't be hidden in-step
// without register spills], epilogue drain+sync+flag/projection ~0.5-1us,
// residual handoff coupling). Per-step work is byte-identical (same A-frag
// reads, 16 MFMAs, gate chain; M-replication 4x->8x costs nothing). LDS
// footprint invariant: xqls 2x32.8K + yst 2x8.2K + ystage 2x8K = 98.4K.
// CRITICAL: the proven R13 prefetch schedule and its inline-asm register
// live ranges are kept EXACTLY (flag u0, tie-test u2 ["+v" + sched_barrier
// rule-#18], issue u3, drain u10) — windows do NOT scale with CH, avoiding
// the R12/R14 stretched-live-range corruption class.
// Risk noted: 32-wide unrolled step loop ~2x code; if L1I thrashes this
// regresses (diagnostic either way; R17 is the fallback).
// Base (R13/R17): unified yst h-exchange, row-XOR-swizzled ystage loaded
// once per WG, steady-state chunk top skips poll/sync/wait, batched sc0sc1
// loads, chunk-end bulk y export / projection, weights in registers.

#define BATCH 128
#define TT    1024
#define HH    128
#define DD    64
#define NB    2
#define CH    32                // chunk steps
#define NG    64                // batch groups per layer
#define NCK   (TT / CH)         // 32
#define BSTR  (CH * 1024 + 8)   // xg LDS bytes per batch
#define YSTR  (CH * 256 + 32)   // y/h stage LDS bytes per batch (+32 pad)
#define SSTR  8192              // A-tile stage bytes per batch (32 rows x 256)

typedef __attribute__((ext_vector_type(4))) float f32x4;
typedef __attribute__((ext_vector_type(8))) short bf16x8;
typedef __attribute__((ext_vector_type(4))) short bf16x4;
typedef __attribute__((ext_vector_type(4))) unsigned u32x4;

union U8 { unsigned long long q[2]; bf16x8 v; };

__device__ inline unsigned short f2bf(float f) {           // RNE
  unsigned u = __builtin_bit_cast(unsigned, f);
  u += 0x7FFFu + ((u >> 16) & 1u);
  return (unsigned short)(u >> 16);
}
__device__ inline float bf2f(unsigned short s) {
  return __builtin_bit_cast(float, (unsigned)s << 16);
}
__device__ inline float fsig(float x) {
  return __builtin_amdgcn_rcpf(1.f + __builtin_amdgcn_exp2f(-1.442695041f * x));
}
__device__ inline float ftanh(float x) {
  return 2.f * __builtin_amdgcn_rcpf(1.f + __builtin_amdgcn_exp2f(-2.885390082f * x)) - 1.f;
}
__device__ inline bf16x8 pack8(f32x4 a, f32x4 b) {
  bf16x8 r;
  r[0]=(short)f2bf(a[0]); r[1]=(short)f2bf(a[1]); r[2]=(short)f2bf(a[2]); r[3]=(short)f2bf(a[3]);
  r[4]=(short)f2bf(b[0]); r[5]=(short)f2bf(b[1]); r[6]=(short)f2bf(b[2]); r[7]=(short)f2bf(b[3]);
  return r;
}
// LDS-only barrier: does NOT drain vmcnt.
__device__ inline void bar_lds() {
  asm volatile("s_waitcnt lgkmcnt(0)\n\ts_barrier" ::: "memory");
}
__device__ inline void ystore8(unsigned short* p, unsigned long long v) {
  __hip_atomic_store((unsigned long long*)p, v, __ATOMIC_RELAXED, __HIP_MEMORY_SCOPE_AGENT);
}

__global__ void init_flags(int* f) { if (threadIdx.x < 128) f[threadIdx.x] = 0; }

__global__ __launch_bounds__(512) void lstm_fused(
    const float* __restrict__ x,
    const float* __restrict__ h0, const float* __restrict__ c0,
    const float* __restrict__ Wih0, const float* __restrict__ Whh0,
    const float* __restrict__ bih0, const float* __restrict__ bhh0,
    const float* __restrict__ Wih1, const float* __restrict__ Whh1,
    const float* __restrict__ bih1, const float* __restrict__ bhh1,
    const float* __restrict__ Wih2, const float* __restrict__ Whh2,
    const float* __restrict__ bih2, const float* __restrict__ bhh2,
    const float* __restrict__ Wout, const float* __restrict__ boutp,
    unsigned short* __restrict__ y0, unsigned short* __restrict__ y1,
    float* __restrict__ outp, float* __restrict__ hN, float* __restrict__ cN,
    int* __restrict__ flags)
{
  __shared__ __align__(16) char xqls[NB * BSTR];   // xg chunk [b][t][j][gate]
  __shared__ __align__(16) char yst[NB * YSTR];    // h stage [b][u][j] — exchange + export + proj
  __shared__ __align__(16) char ystage[NB * SSTR]; // A-tile stage [b][row][256B], row-XOR-swizzled
  __shared__ int rdyf;                              // prefetch-ready broadcast

  const int tid = threadIdx.x, wave = tid >> 6, lane = tid & 63;
  const int quad = lane >> 4, l15 = lane & 15;
  const int layer = blockIdx.x / NG, g = blockIdx.x % NG;
  const int bg0 = g * NB;
  const int bq = quad >> 1;                 // this lane's batch (0..1), 2 quads/batch
  const int gb = bg0 + bq;
  const int j = wave * 16 + l15;

  const float *Wih, *Whh, *bih, *bhh;
  const unsigned short* yin = nullptr;
  unsigned short* yout = nullptr;
  if (layer == 0)      { Wih = Wih0; Whh = Whh0; bih = bih0; bhh = bhh0; yout = y0; }
  else if (layer == 1) { Wih = Wih1; Whh = Whh1; bih = bih1; bhh = bhh1; yin = y0; yout = y1; }
  else                 { Wih = Wih2; Whh = Whh2; bih = bih2; bhh = bhh2; yin = y1; }
  const int Kin = (layer == 0) ? DD : HH;
  const int* fp = flags + (layer > 0 ? (layer - 1) * NG + g : 0);

  // Whh B-frags: tile n = q*128 + j, k = quad*8 + kc*32 + e
  bf16x8 bwh[4][4];
#pragma unroll
  for (int q = 0; q < 4; ++q)
#pragma unroll
    for (int kc = 0; kc < 4; ++kc) {
      const float* p = Whh + (size_t)(q * 128 + j) * HH + quad * 8 + kc * 32;
      bwh[q][kc] = pack8(*(const f32x4*)p, *(const f32x4*)(p + 4));
    }
  // Wih B-frags (K = 64 or 128)
  bf16x8 bwi[4][4];
#pragma unroll
  for (int q = 0; q < 4; ++q)
    for (int kc = 0; kc < Kin / 32; ++kc) {
      const float* p = Wih + (size_t)(q * 128 + j) * Kin + quad * 8 + kc * 32;
      bwi[q][kc] = pack8(*(const f32x4*)p, *(const f32x4*)(p + 4));
    }
  float bs[4];
#pragma unroll
  for (int q = 0; q < 4; ++q) bs[q] = bih[q * 128 + j] + bhh[q * 128 + j];

  // A-tile stage geometry: 2 batches x 32 rows x 256B; thread covers 32B.
  // Swizzle: byte ^= (row&7)<<4.
  const int stg_b = tid >> 8, stg_u = (tid >> 3) & 31, stg_p = tid & 7;
  const int swz_w = (stg_u & 7) << 4;
  const int wr0 = stg_b * SSTR + stg_u * 256 + ((stg_p * 32) ^ swz_w);
  const int wr1 = stg_b * SSTR + stg_u * 256 + ((stg_p * 32 + 16) ^ swz_w);
  const int swz_r = (l15 & 7) << 4;

  const float* h0l = h0 + (size_t)layer * BATCH * HH;
  const float* c0l = c0 + (size_t)layer * BATCH * HH;
  // seed h0 into yst row 31 (step 0 reads row (0+31)&31 = 31)
  *(unsigned short*)(yst + bq * YSTR + 31 * 256 + j * 2) = f2bf(h0l[(size_t)gb * HH + j]);
  float cc = c0l[(size_t)gb * HH + j];

  // projection weights (layer 2): Wout[lg*16 .. lg*16+15] per lane group
  f32x4 wvp0 = {0,0,0,0}, wvp1 = {0,0,0,0}, wvp2 = {0,0,0,0}, wvp3 = {0,0,0,0};
  float ob = 0.f;
  if (layer == 2) {
    const float* wp = Wout + (lane & 7) * 16;
    wvp0 = *(const f32x4*)(wp + 0);
    wvp1 = *(const f32x4*)(wp + 4);
    wvp2 = *(const f32x4*)(wp + 8);
    wvp3 = *(const f32x4*)(wp + 12);
    ob = boutp[0];
  }

  __syncthreads();

  const f32x4 z4 = {0.f, 0.f, 0.f, 0.f};
  float hv = 0.f;
  const int yst_w = bq * YSTR + j * 2;              // + u*256 per step
  // A-frag base: batch = l15>>3 (rows 0-7 = b0, 8-15 = b1, 8x replication)
  const char* abase0 = yst + (l15 >> 3) * YSTR + quad * 16;  // + row*256, +kc*64
  int havepf = 0;

  for (int ck = 0; ck < NCK; ++ck) {
    int t0 = ck * CH;

    // ---- ensure ystage holds this chunk's A-tile ----
    if (!havepf) {
      if (layer > 0) {
        if (tid == 0) {
          while (__hip_atomic_load(fp, __ATOMIC_ACQUIRE, __HIP_MEMORY_SCOPE_AGENT) <= ck)
            __builtin_amdgcn_s_sleep(1);
        }
        __syncthreads();
      }
      u32x4 s0v, s1v;
      if (layer == 0) {
        const float* gp = x + ((size_t)(bg0 + stg_b) * TT + t0 + stg_u) * DD + stg_p * 8;
        asm volatile("global_load_dwordx4 %0, %2, off\n\t"
                     "global_load_dwordx4 %1, %2, off offset:16\n\t"
                     "s_waitcnt vmcnt(0)"
                     : "=&v"(s0v), "=&v"(s1v) : "v"(gp) : "memory");
      } else {
        const unsigned short* gp = yin + ((size_t)(bg0 + stg_b) * TT + t0 + stg_u) * HH + stg_p * 16;
        asm volatile("global_load_dwordx4 %0, %2, off sc0 sc1\n\t"
                     "global_load_dwordx4 %1, %2, off offset:16 sc0 sc1\n\t"
                     "s_waitcnt vmcnt(0)"
                     : "=&v"(s0v), "=&v"(s1v) : "v"(gp) : "memory");
      }
      *(u32x4*)(ystage + wr0) = s0v;
      *(u32x4*)(ystage + wr1) = s1v;
      bar_lds();
    }
    // (prefetched path: stage writes ordered by step barriers — go
    //  straight to GEMM.)

    // ---- fused chunk GEMM from LDS stage: 4 M-tiles ----
    // tile mt: batch b = mt>>1, time-half th = mt&1; A rows = th*16+l15.
    if (layer == 0) {
#pragma unroll
      for (int mt = 0; mt < 4; ++mt) {
        const char* rb = ystage + (mt >> 1) * SSTR + ((mt & 1) * 16 + l15) * 256;
        f32x4 x0 = *(const f32x4*)(rb + ((quad * 32) ^ swz_r));
        f32x4 x1 = *(const f32x4*)(rb + ((quad * 32 + 16) ^ swz_r));
        f32x4 x2 = *(const f32x4*)(rb + ((128 + quad * 32) ^ swz_r));
        f32x4 x3 = *(const f32x4*)(rb + ((128 + quad * 32 + 16) ^ swz_r));
        bf16x8 af0 = pack8(x0, x1);
        bf16x8 af1 = pack8(x2, x3);
        f32x4 acc[4];
#pragma unroll
        for (int q = 0; q < 4; ++q) acc[q] = __builtin_amdgcn_mfma_f32_16x16x32_bf16(af0, bwi[q][0], z4, 0, 0, 0);
#pragma unroll
        for (int q = 0; q < 4; ++q) acc[q] = __builtin_amdgcn_mfma_f32_16x16x32_bf16(af1, bwi[q][1], acc[q], 0, 0, 0);
        char* base = xqls + (mt >> 1) * BSTR + ((mt & 1) * 16 + quad * 4) * 1024 + j * 8;
#pragma unroll
        for (int r = 0; r < 4; ++r) {
          bf16x4 o;
#pragma unroll
          for (int q = 0; q < 4; ++q) o[q] = (short)f2bf(acc[q][r] + bs[q]);
          *(bf16x4*)(base + r * 1024) = o;
        }
      }
    } else {
#pragma unroll
      for (int mt = 0; mt < 4; ++mt) {
        const char* rb = ystage + (mt >> 1) * SSTR + ((mt & 1) * 16 + l15) * 256;
        bf16x8 a4[4];
#pragma unroll
        for (int kc = 0; kc < 4; ++kc)
          a4[kc] = *(const bf16x8*)(rb + ((quad * 16 + kc * 64) ^ swz_r));
        f32x4 acc[4];
#pragma unroll
        for (int q = 0; q < 4; ++q) acc[q] = __builtin_amdgcn_mfma_f32_16x16x32_bf16(a4[0], bwi[q][0], z4, 0, 0, 0);
#pragma unroll
        for (int kc = 1; kc < 4; ++kc)
#pragma unroll
          for (int q = 0; q < 4; ++q) acc[q] = __builtin_amdgcn_mfma_f32_16x16x32_bf16(a4[kc], bwi[q][kc], acc[q], 0, 0, 0);
        char* base = xqls + (mt >> 1) * BSTR + ((mt & 1) * 16 + quad * 4) * 1024 + j * 8;
#pragma unroll
        for (int r = 0; r < 4; ++r) {
          bf16x4 o;
#pragma unroll
          for (int q = 0; q < 4; ++q) o[q] = (short)f2bf(acc[q][r] + bs[q]);
          *(bf16x4*)(base + r * 1024) = o;
        }
      }
    }
    bar_lds();

    // ---- CH recurrence steps (uniform body) + hidden prefetch ----
    unsigned fvp = 0;
    u32x4 pf0, pf1;
#pragma unroll
    for (int u = 0; u < CH; ++u) {
      // A-frags directly from yst row (u+31)&31 (8-lane broadcast reads)
      const char* ab = abase0 + (((u + 31) & 31) * 256);
      bf16x8 a0 = *(const bf16x8*)(ab);
      bf16x8 a1 = *(const bf16x8*)(ab + 64);
      bf16x8 a2 = *(const bf16x8*)(ab + 128);
      bf16x8 a3 = *(const bf16x8*)(ab + 192);
      bf16x4 xq4 = *(const bf16x4*)(xqls + bq * BSTR + u * 1024 + j * 8);

      f32x4 c01[4], c23[4];
#pragma unroll
      for (int q = 0; q < 4; ++q) c01[q] = __builtin_amdgcn_mfma_f32_16x16x32_bf16(a0, bwh[q][0], z4, 0, 0, 0);
#pragma unroll
      for (int q = 0; q < 4; ++q) c23[q] = __builtin_amdgcn_mfma_f32_16x16x32_bf16(a2, bwh[q][2], z4, 0, 0, 0);
#pragma unroll
      for (int q = 0; q < 4; ++q) c01[q] = __builtin_amdgcn_mfma_f32_16x16x32_bf16(a1, bwh[q][1], c01[q], 0, 0, 0);
#pragma unroll
      for (int q = 0; q < 4; ++q) c23[q] = __builtin_amdgcn_mfma_f32_16x16x32_bf16(a3, bwh[q][3], c23[q], 0, 0, 0);

      // C row = quad*4 -> batch (quad*4)>>3 = bq; reg 0 of each acc.
      float gi = fsig(c01[0][0] + c23[0][0] + bf2f((unsigned short)xq4[0]));
      float gf = fsig(c01[1][0] + c23[1][0] + bf2f((unsigned short)xq4[1]));
      float gg = ftanh(c01[2][0] + c23[2][0] + bf2f((unsigned short)xq4[2]));
      float go = fsig(c01[3][0] + c23[3][0] + bf2f((unsigned short)xq4[3]));
      cc = gf * cc + gi * gg;
      hv = go * ftanh(cc);
      unsigned short hb = f2bf(hv);
      // two quads per batch write the same value to the same address
      // (benign same-value LDS write); single store serves exchange+stage.
      *(unsigned short*)(yst + yst_w + u * 256) = hb;

      // ---- prefetch machinery (R13 schedule, UNCHANGED live ranges) ----
      if (u == 0 && layer > 0 && ck + 1 < NCK) {
        asm volatile("global_load_dword %0, %1, off sc0 sc1"
                     : "=&v"(fvp) : "v"(fp) : "memory");
      }
      if (u == 2 && layer > 0 && ck + 1 < NCK) {
        // rule-#18: value tied THROUGH the waitcnt + sched fence
        asm volatile("s_waitcnt vmcnt(0)" : "+v"(fvp) :: "memory");
        __builtin_amdgcn_sched_barrier(0);
        int rdy = __any((int)fvp > ck + 1) ? 1 : 0;     // producer >= ck+2
        if (tid == 0) rdyf = rdy;                       // visible after bar_lds
      }
      if (u == 3) {
        havepf = 0;
        if (ck + 1 < NCK) {
          if (layer == 0) {
            const float* gp = x + ((size_t)(bg0 + stg_b) * TT + t0 + CH + stg_u) * DD + stg_p * 8;
            asm volatile("global_load_dwordx4 %0, %2, off\n\t"
                         "global_load_dwordx4 %1, %2, off offset:16"
                         : "=&v"(pf0), "=&v"(pf1) : "v"(gp) : "memory");
            havepf = 1;
          } else if (rdyf) {
            const unsigned short* gp = yin + ((size_t)(bg0 + stg_b) * TT + t0 + CH + stg_u) * HH + stg_p * 16;
            asm volatile("global_load_dwordx4 %0, %2, off sc0 sc1\n\t"
                         "global_load_dwordx4 %1, %2, off offset:16 sc0 sc1"
                         : "=&v"(pf0), "=&v"(pf1) : "v"(gp) : "memory");
            havepf = 1;
          }
        }
      }
      if (u == 10 && havepf) {
        asm volatile("s_waitcnt vmcnt(0)" ::: "memory"); // prefetch loads done
        __builtin_amdgcn_sched_barrier(0);               // rule-#18 fence
        *(u32x4*)(ystage + wr0) = pf0;                   // ordered ds_writes
        *(u32x4*)(ystage + wr1) = pf1;
      }
      bar_lds();
    }

    // ---- chunk epilogue ----
    if (layer < 2) {
      // bulk y export: 16 KB stage -> global via wide agent-scope stores
#pragma unroll
      for (int s = 0; s < 2; ++s) {
        int seg = tid + s * 512;
        int b = seg >> 9, u = (seg >> 4) & 31, part = seg & 15;
        U8 v; v.v = *(const bf16x8*)(yst + b * YSTR + u * 256 + part * 16);
        size_t di = ((size_t)(bg0 + b) * TT + t0 + u) * HH + part * 8;
        ystore8(yout + di, v.q[0]);
        ystore8(yout + di + 4, v.q[1]);
      }
      asm volatile("s_waitcnt vmcnt(0)" ::: "memory");
      __syncthreads();
      if (tid == 0)
        __hip_atomic_store(flags + layer * NG + g, ck + 1,
                           __ATOMIC_RELAXED, __HIP_MEMORY_SCOPE_AGENT);
    } else {
      // projection: 64 outputs (2 b x 32 u), 8 lanes per output
      int og = lane >> 3, lg = lane & 7;
      int o = wave * 8 + og;
      int b = o >> 5, u = o & 31;
      const char* sp = yst + b * YSTR + u * 256 + lg * 32;
      bf16x8 ha = *(const bf16x8*)sp;
      bf16x8 hbv = *(const bf16x8*)(sp + 16);
      float s = 0.f;
#pragma unroll
      for (int e = 0; e < 4; ++e) s += bf2f((unsigned short)ha[e]) * wvp0[e];
#pragma unroll
      for (int e = 0; e < 4; ++e) s += bf2f((unsigned short)ha[e + 4]) * wvp1[e];
#pragma unroll
      for (int e = 0; e < 4; ++e) s += bf2f((unsigned short)hbv[e]) * wvp2[e];
#pragma unroll
      for (int e = 0; e < 4; ++e) s += bf2f((unsigned short)hbv[e + 4]) * wvp3[e];
      s += __shfl_xor(s, 1);
      s += __shfl_xor(s, 2);
      s += __shfl_xor(s, 4);
      if (lg == 0) outp[(size_t)(bg0 + b) * TT + t0 + u] = fmaxf(s + ob, 0.f);
      // yst reads drain at the next chunk-top bar_lds before step-0
      // overwrites yst; row 31 (read by step 0) is written only at step 31.
    }
  }

  float* hNl = hN + (size_t)layer * BATCH * HH;
  float* cNl = cN + (size_t)layer * BATCH * HH;
  hNl[(size_t)gb * HH + j] = hv;   // 2 quads/batch: same value, same addr
  cNl[(size_t)gb * HH + j] = cc;
}

// ---------------- launch ----------------
extern "C" void kernel_launch(void* const* d_in, const int* in_sizes, int n_in,
                              void* d_out, int out_size, void* d_ws, size_t ws_size,
                              hipStream_t stream) {
  const float* x  = (const float*)d_in[0];
  const float* h0 = (const float*)d_in[1];
  const float* c0 = (const float*)d_in[2];
  const float* Wih[3] = {(const float*)d_in[3], (const float*)d_in[7],  (const float*)d_in[11]};
  const float* Whh[3] = {(const float*)d_in[4], (const float*)d_in[8],  (const float*)d_in[12]};
  const float* bih[3] = {(const float*)d_in[5], (const float*)d_in[9],  (const float*)d_in[13]};
  const float* bhh[3] = {(const float*)d_in[6], (const float*)d_in[10], (const float*)d_in[14]};
  const float* Wout = (const float*)d_in[15];
  const float* bout = (const float*)d_in[16];

  float* outp = (float*)d_out;                 // [B][T]
  float* hN = outp + BATCH * TT;               // [L][B][H]
  float* cN = hN + 3 * BATCH * HH;

  char* ws = (char*)d_ws;
  int* flags = (int*)ws;                                            // 128 ints
  unsigned short* y0 = (unsigned short*)(ws + 4096);                // 32 MB
  unsigned short* y1 = (unsigned short*)(ws + 4096 + (size_t)BATCH * TT * HH * 2);

  init_flags<<<1, 128, 0, stream>>>(flags);
  lstm_fused<<<3 * NG, 512, 0, stream>>>(
      x, h0, c0,
      Wih[0], Whh[0], bih[0], bhh[0],
      Wih[1], Whh[1], bih[1], bhh[1],
      Wih[2], Whh[2], bih[2], bhh[2],
      Wout, bout, y0, y1, outp, hN, cN, flags);
}